// Round 14
// baseline (193.539 us; speedup 1.0000x reference)
//
#include <hip/hip_runtime.h>
#include <hip/hip_bf16.h>

// B=4, S=2048, TEXT_DIM=768, VISION_DIM=768, HIDDEN=512, HEADS=8, HEAD_DIM=64
#define BATCH 4
#define SEQ 2048
#define TDIM 768
#define VDIM 768
#define HID 512
#define NHEADS 8
#define HDIM 64
#define MROWS (BATCH * SEQ)   // 8192
#define NQKV (3 * HID)        // 1536
#define NCONV (MROWS * TDIM / 1024)   // 6144 conv blocks

typedef unsigned short ushort_t;
typedef __attribute__((ext_vector_type(8))) short short8;
typedef __attribute__((ext_vector_type(4))) short short4v;
typedef __attribute__((ext_vector_type(4))) float floatx4;

// 0.125 * log2(e): folded into Q so softmax uses exp2
#define QSCALE 0.18033688011112042f

__device__ __forceinline__ ushort_t bf16_rne(float f) {
    unsigned int u = __float_as_uint(f);
    u = (u + 0x7fffu + ((u >> 16) & 1u)) >> 16;
    return (ushort_t)u;
}

__device__ __forceinline__ void async16(const ushort_t* g, ushort_t* l) {
    __builtin_amdgcn_global_load_lds(
        (const __attribute__((address_space(1))) unsigned int*)g,
        (__attribute__((address_space(3))) unsigned int*)l, 16, 0, 0);
}

// ---------------------------------------------------------------------------
// Merged pre-pass: conv (X fp32->bf16) + weight transposes, ONE dispatch.
// (round-13 verified)
// ---------------------------------------------------------------------------
__global__ __launch_bounds__(256) void prepass(
    const float* __restrict__ X,
    const float* __restrict__ Wq, const float* __restrict__ Wk,
    const float* __restrict__ Wv, const float* __restrict__ Wo,
    ushort_t* __restrict__ Xb,
    ushort_t* __restrict__ Wqkvt, ushort_t* __restrict__ Wot)
{
    __shared__ float tile[32][33];
    const int bx = blockIdx.x;

    if (bx < NCONV) {   // ---- conv region ----
        const int i = (bx * 256 + threadIdx.x) * 4;
        const floatx4 v = *(const floatx4*)(X + i);
        short4v o;
#pragma unroll
        for (int j = 0; j < 4; ++j) o[j] = (short)bf16_rne(v[j]);
        *(short4v*)(Xb + i) = o;
        return;
    }

    // ---- transp region ----
    const int t  = bx - NCONV;
    const int z  = t / 576;           // 0..3
    const int r  = t - z * 576;
    const int by = r / 24;
    const int bxx = r - by * 24;

    const float* src;
    ushort_t* dst;
    int R, C;
    if (z < 3) {
        src = (z == 0) ? Wq : (z == 1) ? Wk : Wv;
        dst = Wqkvt + (size_t)z * HID * TDIM;
        R = TDIM; C = HID;
    } else {
        src = Wo; dst = Wot; R = HID; C = VDIM;
    }
    const int tx = threadIdx.x & 31, ty = threadIdx.x >> 5;  // 32 x 8
    const int c0 = bxx * 32, r0 = by * 32;
    if (c0 >= C || r0 >= R) return;
#pragma unroll
    for (int i = 0; i < 4; ++i)
        tile[ty + i * 8][tx] = src[(size_t)(r0 + ty + i * 8) * C + c0 + tx];
    __syncthreads();
#pragma unroll
    for (int i = 0; i < 4; ++i)
        dst[(size_t)(c0 + ty + i * 8) * R + r0 + tx] = bf16_rne(tile[tx][ty + i * 8]);
}

// ---------------------------------------------------------------------------
// bf16 MFMA GEMM mainloop: C(128x128) = A[M][K] x Bt[N][K]^T.
// Round-14: flash-v3-style double-buffered PREFETCH. Round-13 showed the two
// GEMMs consume ~80-95 us combined (~300 TF) while the old loop exposed full
// stage latency every K-step: async16 -> barrier(vmcnt 0) -> compute. New
// cadence (verbatim from the thrice-verified flash skeleton, 1 barrier/tile):
//   stage(0,0); { barrier; stage(1,kt+64); compute(0);
//                 barrier; if(more) stage(0,kt+128); compute(1); }
// Re-stage of a buffer happens only after the barrier following its compute
// (same race-safety argument as flash v3). LDS 32->64 KB.
// XOR swizzle (round-9: conflicts -> 0) unchanged.
// ---------------------------------------------------------------------------
template<int KD, bool SWAPPED>
__device__ __forceinline__ void gemm128(
    const ushort_t* __restrict__ A, const ushort_t* __restrict__ Bt,
    int m0, int n0, ushort_t* As, ushort_t* Bs, floatx4 (&acc)[4][4])
{
    const int tid  = threadIdx.x;
    const int lane = tid & 63;
    const int w    = tid >> 6;
    const int l15  = lane & 15;
    const int quad = lane >> 4;
    const int wrow = w >> 1;
    const int wcol = w & 1;

    const int srow = lane >> 3;                  // 0..7 = row&7
    const int scol = ((lane & 7) ^ srow) * 8;    // swizzled k elem offset

    const ushort_t* ga = A  + (size_t)(m0 + w * 32 + srow) * KD + scol;
    const ushort_t* gb = Bt + (size_t)(n0 + w * 32 + srow) * KD + scol;

    auto stage = [&](int buf, int kt) {
        ushort_t* la = As + buf * (128 * 64) + (w * 32) * 64;
        ushort_t* lb = Bs + buf * (128 * 64) + (w * 32) * 64;
#pragma unroll
        for (int i = 0; i < 4; ++i) {
            async16(ga + (size_t)(i * 8) * KD + kt, la + i * 8 * 64);
            async16(gb + (size_t)(i * 8) * KD + kt, lb + i * 8 * 64);
        }
    };

    auto compute = [&](int buf) {
        const ushort_t* as = As + buf * (128 * 64);
        const ushort_t* bs = Bs + buf * (128 * 64);
#pragma unroll
        for (int half = 0; half < 2; ++half) {
            const int kk = ((half * 4 + quad) ^ (l15 & 7)) * 8;
            short8 af[4], bf[4];
#pragma unroll
            for (int t = 0; t < 4; ++t) {
                af[t] = *(const short8*)&as[(wrow * 64 + t * 16 + l15) * 64 + kk];
                bf[t] = *(const short8*)&bs[(wcol * 64 + t * 16 + l15) * 64 + kk];
            }
#pragma unroll
            for (int mi = 0; mi < 4; ++mi)
#pragma unroll
                for (int ni = 0; ni < 4; ++ni) {
                    if (SWAPPED)
                        acc[mi][ni] = __builtin_amdgcn_mfma_f32_16x16x32_bf16(
                            bf[ni], af[mi], acc[mi][ni], 0, 0, 0);
                    else
                        acc[mi][ni] = __builtin_amdgcn_mfma_f32_16x16x32_bf16(
                            af[mi], bf[ni], acc[mi][ni], 0, 0, 0);
                }
        }
    };

    // prologue: tile 0 into buf0
    stage(0, 0);

    for (int kt = 0; kt < KD; kt += 128) {
        __syncthreads();                          // drains buf0 loads
        stage(1, kt + 64);                        // prefetch buf1
        compute(0);

        __syncthreads();                          // drains buf1 loads
        if (kt + 128 < KD) stage(0, kt + 128);    // prefetch buf0
        compute(1);
    }
}

// ---------------------------------------------------------------------------
// Kernel 1: QKV projection, bf16 MFMA.  Grid (12, 64).
// ---------------------------------------------------------------------------
__global__ __launch_bounds__(256) void qkv_gemm_mfma(
    const ushort_t* __restrict__ Xb, const ushort_t* __restrict__ Wt,
    const float* __restrict__ bq, const float* __restrict__ bk,
    const float* __restrict__ bv,
    ushort_t* __restrict__ Q, ushort_t* __restrict__ K, ushort_t* __restrict__ V)
{
    __shared__ __align__(16) ushort_t As[2 * 128 * 64];
    __shared__ __align__(16) ushort_t Bs[2 * 128 * 64];

    const int bx = blockIdx.x;          // 0..11
    const int m0 = blockIdx.y * 128;
    const int n0 = bx * 128;
    const int which = bx >> 2;          // 0=Q 1=K 2=V
    const bool isV = (which == 2);

    floatx4 acc[4][4];
#pragma unroll
    for (int i = 0; i < 4; ++i)
#pragma unroll
        for (int j = 0; j < 4; ++j) acc[i][j] = (floatx4)0.0f;

    if (isV) gemm128<TDIM, false>(Xb, Wt, m0, n0, As, Bs, acc);
    else     gemm128<TDIM, true >(Xb, Wt, m0, n0, As, Bs, acc);

    const int lane = threadIdx.x & 63;
    const int w    = threadIdx.x >> 6;
    const int l15  = lane & 15;
    const int quad = lane >> 4;
    const int wrow = w >> 1;
    const int wcol = w & 1;

    if (!isV) {
        const float* bias = (which == 0) ? bq : bk;
        const float scale = (which == 0) ? QSCALE : 1.0f;
        ushort_t* Out = (which == 0) ? Q : K;
#pragma unroll
        for (int mi = 0; mi < 4; ++mi) {
            const int m = m0 + wrow * 64 + mi * 16 + l15;
            const int b = m >> 11;
            const int s = m & 2047;
#pragma unroll
            for (int ni = 0; ni < 4; ++ni) {
                const int c = (n0 - which * HID) + wcol * 64 + ni * 16 + quad * 4;
                const int h = c >> 6;
                const int d0 = c & 63;
                const floatx4 b4 = *(const floatx4*)(bias + c);
                short4v pk;
#pragma unroll
                for (int r = 0; r < 4; ++r)
                    pk[r] = (short)bf16_rne((acc[mi][ni][r] + b4[r]) * scale);
                *(short4v*)&Out[((size_t)(b * NHEADS + h) * SEQ + s) * HDIM + d0] = pk;
            }
        }
    } else {
#pragma unroll
        for (int ni = 0; ni < 4; ++ni) {
            const int c = (n0 - 2 * HID) + wcol * 64 + ni * 16 + l15;
            const int h = c >> 6;
            const int d = c & 63;
            const float b1 = bv[c];
#pragma unroll
            for (int mi = 0; mi < 4; ++mi) {
                const int mb = m0 + wrow * 64 + mi * 16 + quad * 4;
                const int b = mb >> 11;
                const int s0 = mb & 2047;
                short4v pk;
#pragma unroll
                for (int r = 0; r < 4; ++r)
                    pk[r] = (short)bf16_rne(acc[mi][ni][r] + b1);
                *(short4v*)&V[((size_t)(b * NHEADS + h) * HDIM + d) * SEQ + s0] = pk;
            }
        }
    }
}

// ---------------------------------------------------------------------------
// Kernel 2: MFMA flash attention — v3 VERBATIM (round-1/9/13: 47.7-48 us,
// passed, absmax 4.88e-4; within 17% of its 41-us LDS-pipe floor).
// Closed lines: dual-qi 16x16 (2x miscompute); direct-global K (134 us);
// 32x32 family incl. kv-split (50.4 best).
// ---------------------------------------------------------------------------
__global__ __launch_bounds__(512) void flash_attn_mfma(
    const ushort_t* __restrict__ Q, const ushort_t* __restrict__ K,
    const ushort_t* __restrict__ Vt, ushort_t* __restrict__ Att)
{
    __shared__ __align__(16) ushort_t Ks[2][64 * 64];   // [buf][kk][d]  (swizzled)
    __shared__ __align__(16) ushort_t Vs[2][64 * 64];   // [buf][d][kk]  (swizzled)

    const int tid  = threadIdx.x;
    const int lane = tid & 63;
    const int w    = tid >> 6;     // wave 0..7
    const int l15  = lane & 15;
    const int quad = lane >> 4;

    const int bh = blockIdx.y;
    const int b  = bh >> 3;
    const int h  = bh & 7;
    const int q0 = blockIdx.x * 128;

    const ushort_t* Qb = Q  + (size_t)bh * SEQ * HDIM;
    const ushort_t* Kb = K  + (size_t)bh * SEQ * HDIM;
    const ushort_t* Vb = Vt + (size_t)bh * HDIM * SEQ;

    // Q fragments (registers, whole kernel). B-operand: n=q=l15, k=d=quad*8+j
    short8 qf0, qf1;
    {
        const ushort_t* qrow = Qb + (size_t)(q0 + w * 16 + l15) * HDIM + quad * 8;
        qf0 = *(const short8*)(qrow);
        qf1 = *(const short8*)(qrow + 32);
    }

    floatx4 of[4];
#pragma unroll
    for (int t = 0; t < 4; ++t) of[t] = (floatx4)0.0f;
    floatx4 ofl = (floatx4)0.0f;          // l accumulator via ones-MFMA

    short8 ones;
#pragma unroll
    for (int j = 0; j < 8; ++j) ones[j] = (short)0x3F80;   // bf16 1.0

    const floatx4 z4 = (floatx4)0.0f;

    // staging: wave w stages rows w*8..w*8+7 of each tile.
    // global source col16 is pre-swizzled so the LINEAR global_load_lds dest
    // (base + lane*16) lands the XOR-swizzled layout.
    const int srow = lane >> 3;                    // 0..7 = row&7
    const int scol = ((lane & 7) ^ srow) * 8;      // swizzled col (elems)
    const ushort_t* gk = Kb + (size_t)(w * 8 + srow) * HDIM + scol;
    const ushort_t* gv = Vb + (size_t)(w * 8 + srow) * SEQ + scol;
    ushort_t* lk0 = &Ks[0][w * 8 * 64];            // wave-uniform LDS bases
    ushort_t* lk1 = &Ks[1][w * 8 * 64];
    ushort_t* lv0 = &Vs[0][w * 8 * 64];
    ushort_t* lv1 = &Vs[1][w * 8 * 64];

    // fragment read offsets (swizzle-aware): global col16 c of row r sits at
    // LDS slot c ^ (r&7); r&7 == l15&7 for all t (t*16 = 0 mod 8).
    const int off0 = (quad ^ (l15 & 7)) * 8;       // elems, kv/d half 0
    const int off1 = off0 ^ 32;                    // (slot^4)*8, half 1

    auto tile = [&](const ushort_t* Kt, const ushort_t* Vt_) {
        // ---- S^T = K . Q^T ----
        floatx4 sacc[4];
        __builtin_amdgcn_s_setprio(1);
#pragma unroll
        for (int t = 0; t < 4; ++t) {
            const short8 kf0 = *(const short8*)&Kt[(t * 16 + l15) * 64 + off0];
            const short8 kf1 = *(const short8*)&Kt[(t * 16 + l15) * 64 + off1];
            floatx4 a = z4;
            a = __builtin_amdgcn_mfma_f32_16x16x32_bf16(kf0, qf0, a, 0, 0, 0);
            a = __builtin_amdgcn_mfma_f32_16x16x32_bf16(kf1, qf1, a, 0, 0, 0);
            sacc[t] = a;
        }
        __builtin_amdgcn_s_setprio(0);

        // ---- p = exp2(s) (raw v_exp_f32), pack pairs to bf16x2 ----
        // lane holds p for q=l15, kv = 16t + 4*quad + r
        unsigned w0[4], w1[4];
#pragma unroll
        for (int t = 0; t < 4; ++t) {
            const float p0 = __builtin_amdgcn_exp2f(sacc[t][0]);
            const float p1 = __builtin_amdgcn_exp2f(sacc[t][1]);
            const float p2 = __builtin_amdgcn_exp2f(sacc[t][2]);
            const float p3 = __builtin_amdgcn_exp2f(sacc[t][3]);
            asm("v_cvt_pk_bf16_f32 %0, %1, %2" : "=v"(w0[t]) : "v"(p0), "v"(p1));
            asm("v_cvt_pk_bf16_f32 %0, %1, %2" : "=v"(w1[t]) : "v"(p2), "v"(p3));
        }

        // ---- in-register P^T redistribution (dest b5'=t, b4'=src b5) ----
        unsigned a0 = w0[0], b0 = w0[1];
        asm("v_permlane32_swap_b32 %0, %1" : "+v"(a0), "+v"(b0));
        asm("v_permlane16_swap_b32 %0, %1" : "+v"(a0), "+v"(b0));
        unsigned a1 = w1[0], b1 = w1[1];
        asm("v_permlane32_swap_b32 %0, %1" : "+v"(a1), "+v"(b1));
        asm("v_permlane16_swap_b32 %0, %1" : "+v"(a1), "+v"(b1));
        unsigned a2 = w0[2], b2 = w0[3];
        asm("v_permlane32_swap_b32 %0, %1" : "+v"(a2), "+v"(b2));
        asm("v_permlane16_swap_b32 %0, %1" : "+v"(a2), "+v"(b2));
        unsigned a3 = w1[2], b3 = w1[3];
        asm("v_permlane32_swap_b32 %0, %1" : "+v"(a3), "+v"(b3));
        asm("v_permlane16_swap_b32 %0, %1" : "+v"(a3), "+v"(b3));

        union { unsigned u[4]; short8 s; } P0, P1;
        P0.u[0] = a0; P0.u[1] = a1; P0.u[2] = b0; P0.u[3] = b1;   // kv 0..31
        P1.u[0] = a2; P1.u[1] = a3; P1.u[2] = b2; P1.u[3] = b3;   // kv 32..63
        const short8 pf0 = P0.s;
        const short8 pf1 = P1.s;

        // ---- O^T += V^T . P^T ; l += 1 . P^T (MFMA pipe) ----
        __builtin_amdgcn_s_setprio(1);
        ofl = __builtin_amdgcn_mfma_f32_16x16x32_bf16(ones, pf0, ofl, 0, 0, 0);
        ofl = __builtin_amdgcn_mfma_f32_16x16x32_bf16(ones, pf1, ofl, 0, 0, 0);
#pragma unroll
        for (int t = 0; t < 4; ++t) {
            const short8 vf0 = *(const short8*)&Vt_[(t * 16 + l15) * 64 + off0];
            const short8 vf1 = *(const short8*)&Vt_[(t * 16 + l15) * 64 + off1];
            of[t] = __builtin_amdgcn_mfma_f32_16x16x32_bf16(vf0, pf0, of[t], 0, 0, 0);
            of[t] = __builtin_amdgcn_mfma_f32_16x16x32_bf16(vf1, pf1, of[t], 0, 0, 0);
        }
        __builtin_amdgcn_s_setprio(0);
    };

    // prologue: tile 0 into buf0
    async16(gk, lk0);
    async16(gv, lv0);

    for (int kt = 0; kt < SEQ; kt += 128) {
        __syncthreads();                       // drains buf0 loads (vmcnt(0))
        async16(gk + (size_t)(kt + 64) * HDIM, lk1);   // prefetch buf1
        async16(gv + (kt + 64), lv1);
        tile(Ks[0], Vs[0]);

        __syncthreads();                       // drains buf1 loads
        if (kt + 128 < SEQ) {
            async16(gk + (size_t)(kt + 128) * HDIM, lk0);  // prefetch buf0
            async16(gv + (kt + 128), lv0);
        }
        tile(Ks[1], Vs[1]);
    }

    // ---- epilogue: each lane already holds full l for its q=l15 ----
    const float inv = 1.f / ofl[0];

    const int s = q0 + w * 16 + l15;
    ushort_t* arow = Att + ((size_t)(b * SEQ + s)) * HID + h * HDIM;
#pragma unroll
    for (int t = 0; t < 4; ++t) {
        short4v pk;
#pragma unroll
        for (int r = 0; r < 4; ++r) pk[r] = (short)bf16_rne(of[t][r] * inv);
        *(short4v*)&arow[t * 16 + quad * 4] = pk;
    }
}

// ---------------------------------------------------------------------------
// Kernel 3: output projection, bf16 MFMA.  Grid (6, 64).
// ---------------------------------------------------------------------------
__global__ __launch_bounds__(256) void out_gemm_mfma(
    const ushort_t* __restrict__ Attb, const ushort_t* __restrict__ Wot,
    const float* __restrict__ bo, float* __restrict__ Y)
{
    __shared__ __align__(16) ushort_t As[2 * 128 * 64];
    __shared__ __align__(16) ushort_t Bs[2 * 128 * 64];

    const int m0 = blockIdx.y * 128;
    const int n0 = blockIdx.x * 128;

    floatx4 acc[4][4];
#pragma unroll
    for (int i = 0; i < 4; ++i)
#pragma unroll
        for (int j = 0; j < 4; ++j) acc[i][j] = (floatx4)0.0f;

    gemm128<HID, true>(Attb, Wot, m0, n0, As, Bs, acc);

    const int lane = threadIdx.x & 63;
    const int w    = threadIdx.x >> 6;
    const int l15  = lane & 15;
    const int quad = lane >> 4;
    const int wrow = w >> 1;
    const int wcol = w & 1;

#pragma unroll
    for (int mi = 0; mi < 4; ++mi) {
        const int m = m0 + wrow * 64 + mi * 16 + l15;
#pragma unroll
        for (int ni = 0; ni < 4; ++ni) {
            const int nb = n0 + wcol * 64 + ni * 16 + quad * 4;
            const floatx4 b4 = *(const floatx4*)(bo + nb);
            floatx4 o;
#pragma unroll
            for (int r = 0; r < 4; ++r) o[r] = acc[mi][ni][r] + b4[r];
            *(floatx4*)&Y[(size_t)m * VDIM + nb] = o;
        }
    }
}

// ---------------------------------------------------------------------------
extern "C" void kernel_launch(void* const* d_in, const int* in_sizes, int n_in,
                              void* d_out, int out_size, void* d_ws, size_t ws_size,
                              hipStream_t stream)
{
    const float* text = (const float*)d_in[0];
    const float* Wq = (const float*)d_in[1];
    const float* bq = (const float*)d_in[2];
    const float* Wk = (const float*)d_in[3];
    const float* bk = (const float*)d_in[4];
    const float* Wv = (const float*)d_in[5];
    const float* bv = (const float*)d_in[6];
    const float* Wo = (const float*)d_in[7];
    const float* bo = (const float*)d_in[8];
    float* out = (float*)d_out;

    // ws layout (bf16): Xb | Wqkvt | Wot | Q | K | Vt | Attb  (~49 MB)
    ushort_t* Xb    = (ushort_t*)d_ws;
    ushort_t* Wqkvt = Xb + (size_t)MROWS * TDIM;
    ushort_t* Wot   = Wqkvt + (size_t)NQKV * TDIM;
    ushort_t* Qw    = Wot + (size_t)VDIM * HID;
    ushort_t* Kw    = Qw + (size_t)MROWS * HID;
    ushort_t* Vtw   = Kw + (size_t)MROWS * HID;
    ushort_t* Attb  = Vtw + (size_t)MROWS * HID;

    prepass<<<dim3(NCONV + 4 * 576), 256, 0, stream>>>(
        text, Wq, Wk, Wv, Wo, Xb, Wqkvt, Wot);
    qkv_gemm_mfma<<<dim3(12, 64), 256, 0, stream>>>(Xb, Wqkvt, bq, bk, bv, Qw, Kw, Vtw);
    flash_attn_mfma<<<dim3(16, 32), 512, 0, stream>>>(Qw, Kw, Vtw, Attb);
    out_gemm_mfma<<<dim3(6, 64), 256, 0, stream>>>(Attb, Wot, bo, out);
}

// Round 15
// 179.706 us; speedup vs baseline: 1.0770x; 1.0770x over previous
//
#include <hip/hip_runtime.h>
#include <hip/hip_bf16.h>

// B=4, S=2048, TEXT_DIM=768, VISION_DIM=768, HIDDEN=512, HEADS=8, HEAD_DIM=64
#define BATCH 4
#define SEQ 2048
#define TDIM 768
#define VDIM 768
#define HID 512
#define NHEADS 8
#define HDIM 64
#define MROWS (BATCH * SEQ)   // 8192
#define NQKV (3 * HID)        // 1536
#define NCONV (MROWS * TDIM / 1024)   // 6144 conv blocks

typedef unsigned short ushort_t;
typedef __attribute__((ext_vector_type(8))) short short8;
typedef __attribute__((ext_vector_type(4))) short short4v;
typedef __attribute__((ext_vector_type(4))) float floatx4;

// 0.125 * log2(e): folded into Q so softmax uses exp2
#define QSCALE 0.18033688011112042f

__device__ __forceinline__ ushort_t bf16_rne(float f) {
    unsigned int u = __float_as_uint(f);
    u = (u + 0x7fffu + ((u >> 16) & 1u)) >> 16;
    return (ushort_t)u;
}

__device__ __forceinline__ void async16(const ushort_t* g, ushort_t* l) {
    __builtin_amdgcn_global_load_lds(
        (const __attribute__((address_space(1))) unsigned int*)g,
        (__attribute__((address_space(3))) unsigned int*)l, 16, 0, 0);
}

// ---------------------------------------------------------------------------
// Merged pre-pass: conv (X fp32->bf16) + weight transposes, ONE dispatch.
// (round-13 verified)
// ---------------------------------------------------------------------------
__global__ __launch_bounds__(256) void prepass(
    const float* __restrict__ X,
    const float* __restrict__ Wq, const float* __restrict__ Wk,
    const float* __restrict__ Wv, const float* __restrict__ Wo,
    ushort_t* __restrict__ Xb,
    ushort_t* __restrict__ Wqkvt, ushort_t* __restrict__ Wot)
{
    __shared__ float tile[32][33];
    const int bx = blockIdx.x;

    if (bx < NCONV) {   // ---- conv region ----
        const int i = (bx * 256 + threadIdx.x) * 4;
        const floatx4 v = *(const floatx4*)(X + i);
        short4v o;
#pragma unroll
        for (int j = 0; j < 4; ++j) o[j] = (short)bf16_rne(v[j]);
        *(short4v*)(Xb + i) = o;
        return;
    }

    // ---- transp region ----
    const int t  = bx - NCONV;
    const int z  = t / 576;           // 0..3
    const int r  = t - z * 576;
    const int by = r / 24;
    const int bxx = r - by * 24;

    const float* src;
    ushort_t* dst;
    int R, C;
    if (z < 3) {
        src = (z == 0) ? Wq : (z == 1) ? Wk : Wv;
        dst = Wqkvt + (size_t)z * HID * TDIM;
        R = TDIM; C = HID;
    } else {
        src = Wo; dst = Wot; R = HID; C = VDIM;
    }
    const int tx = threadIdx.x & 31, ty = threadIdx.x >> 5;  // 32 x 8
    const int c0 = bxx * 32, r0 = by * 32;
    if (c0 >= C || r0 >= R) return;
#pragma unroll
    for (int i = 0; i < 4; ++i)
        tile[ty + i * 8][tx] = src[(size_t)(r0 + ty + i * 8) * C + c0 + tx];
    __syncthreads();
#pragma unroll
    for (int i = 0; i < 4; ++i)
        dst[(size_t)(c0 + ty + i * 8) * R + r0 + tx] = bf16_rne(tile[tx][ty + i * 8]);
}

// ---------------------------------------------------------------------------
// m97-style bf16 MFMA GEMM mainloop: C(128x128) = A[M][K] x Bt[N][K]^T.
// Round-9 verified: XOR-swizzled LDS, single-buffer, 3 blocks/CU TLP.
// (Round-14 lesson: dbuf prefetch costs occupancy at a net loss here.)
// ---------------------------------------------------------------------------
template<int KD, bool SWAPPED>
__device__ __forceinline__ void gemm128(
    const ushort_t* __restrict__ A, const ushort_t* __restrict__ Bt,
    int m0, int n0, ushort_t* As, ushort_t* Bs, floatx4 (&acc)[4][4])
{
    const int tid  = threadIdx.x;
    const int lane = tid & 63;
    const int w    = tid >> 6;
    const int l15  = lane & 15;
    const int quad = lane >> 4;
    const int wrow = w >> 1;
    const int wcol = w & 1;

    const int srow = lane >> 3;                  // 0..7 = row&7
    const int scol = ((lane & 7) ^ srow) * 8;    // swizzled k elem offset

    const ushort_t* ga = A  + (size_t)(m0 + w * 32 + srow) * KD + scol;
    const ushort_t* gb = Bt + (size_t)(n0 + w * 32 + srow) * KD + scol;
    ushort_t* la = As + (w * 32) * 64;
    ushort_t* lb = Bs + (w * 32) * 64;

    for (int kt = 0; kt < KD; kt += 64) {
#pragma unroll
        for (int i = 0; i < 4; ++i) {
            async16(ga + (size_t)(i * 8) * KD + kt, la + i * 8 * 64);
            async16(gb + (size_t)(i * 8) * KD + kt, lb + i * 8 * 64);
        }
        __syncthreads();
#pragma unroll
        for (int half = 0; half < 2; ++half) {
            const int kk = ((half * 4 + quad) ^ (l15 & 7)) * 8;
            short8 af[4], bf[4];
#pragma unroll
            for (int t = 0; t < 4; ++t) {
                af[t] = *(const short8*)&As[(wrow * 64 + t * 16 + l15) * 64 + kk];
                bf[t] = *(const short8*)&Bs[(wcol * 64 + t * 16 + l15) * 64 + kk];
            }
#pragma unroll
            for (int mi = 0; mi < 4; ++mi)
#pragma unroll
                for (int ni = 0; ni < 4; ++ni) {
                    if (SWAPPED)
                        acc[mi][ni] = __builtin_amdgcn_mfma_f32_16x16x32_bf16(
                            bf[ni], af[mi], acc[mi][ni], 0, 0, 0);
                    else
                        acc[mi][ni] = __builtin_amdgcn_mfma_f32_16x16x32_bf16(
                            af[mi], bf[ni], acc[mi][ni], 0, 0, 0);
                }
        }
        __syncthreads();
    }
}

// ---------------------------------------------------------------------------
// Kernel 1: QKV projection, bf16 MFMA.  Grid (12, 64) — round-9 verified.
// ---------------------------------------------------------------------------
__global__ __launch_bounds__(256) void qkv_gemm_mfma(
    const ushort_t* __restrict__ Xb, const ushort_t* __restrict__ Wt,
    const float* __restrict__ bq, const float* __restrict__ bk,
    const float* __restrict__ bv,
    ushort_t* __restrict__ Q, ushort_t* __restrict__ K, ushort_t* __restrict__ V)
{
    __shared__ __align__(16) ushort_t As[128 * 64];
    __shared__ __align__(16) ushort_t Bs[128 * 64];

    const int bx = blockIdx.x;          // 0..11
    const int m0 = blockIdx.y * 128;
    const int n0 = bx * 128;
    const int which = bx >> 2;          // 0=Q 1=K 2=V
    const bool isV = (which == 2);

    floatx4 acc[4][4];
#pragma unroll
    for (int i = 0; i < 4; ++i)
#pragma unroll
        for (int j = 0; j < 4; ++j) acc[i][j] = (floatx4)0.0f;

    if (isV) gemm128<TDIM, false>(Xb, Wt, m0, n0, As, Bs, acc);
    else     gemm128<TDIM, true >(Xb, Wt, m0, n0, As, Bs, acc);

    const int lane = threadIdx.x & 63;
    const int w    = threadIdx.x >> 6;
    const int l15  = lane & 15;
    const int quad = lane >> 4;
    const int wrow = w >> 1;
    const int wcol = w & 1;

    if (!isV) {
        const float* bias = (which == 0) ? bq : bk;
        const float scale = (which == 0) ? QSCALE : 1.0f;
        ushort_t* Out = (which == 0) ? Q : K;
#pragma unroll
        for (int mi = 0; mi < 4; ++mi) {
            const int m = m0 + wrow * 64 + mi * 16 + l15;
            const int b = m >> 11;
            const int s = m & 2047;
#pragma unroll
            for (int ni = 0; ni < 4; ++ni) {
                const int c = (n0 - which * HID) + wcol * 64 + ni * 16 + quad * 4;
                const int h = c >> 6;
                const int d0 = c & 63;
                const floatx4 b4 = *(const floatx4*)(bias + c);
                short4v pk;
#pragma unroll
                for (int r = 0; r < 4; ++r)
                    pk[r] = (short)bf16_rne((acc[mi][ni][r] + b4[r]) * scale);
                *(short4v*)&Out[((size_t)(b * NHEADS + h) * SEQ + s) * HDIM + d0] = pk;
            }
        }
    } else {
#pragma unroll
        for (int ni = 0; ni < 4; ++ni) {
            const int c = (n0 - 2 * HID) + wcol * 64 + ni * 16 + l15;
            const int h = c >> 6;
            const int d = c & 63;
            const float b1 = bv[c];
#pragma unroll
            for (int mi = 0; mi < 4; ++mi) {
                const int mb = m0 + wrow * 64 + mi * 16 + quad * 4;
                const int b = mb >> 11;
                const int s0 = mb & 2047;
                short4v pk;
#pragma unroll
                for (int r = 0; r < 4; ++r)
                    pk[r] = (short)bf16_rne(acc[mi][ni][r] + b1);
                *(short4v*)&V[((size_t)(b * NHEADS + h) * HDIM + d) * SEQ + s0] = pk;
            }
        }
    }
}

// ---------------------------------------------------------------------------
// Kernel 2: MFMA flash attention — v3 VERBATIM (round-1/9/13: 47.7-48 us,
// passed, absmax 4.88e-4; within 17% of its 41-us LDS-pipe floor).
// Closed lines: dual-qi 16x16 (2x miscompute); direct-global K (134 us);
// 32x32 family incl. kv-split (50.4 best); GEMM-side dbuf (occupancy loss).
// ---------------------------------------------------------------------------
__global__ __launch_bounds__(512) void flash_attn_mfma(
    const ushort_t* __restrict__ Q, const ushort_t* __restrict__ K,
    const ushort_t* __restrict__ Vt, ushort_t* __restrict__ Att)
{
    __shared__ __align__(16) ushort_t Ks[2][64 * 64];   // [buf][kk][d]  (swizzled)
    __shared__ __align__(16) ushort_t Vs[2][64 * 64];   // [buf][d][kk]  (swizzled)

    const int tid  = threadIdx.x;
    const int lane = tid & 63;
    const int w    = tid >> 6;     // wave 0..7
    const int l15  = lane & 15;
    const int quad = lane >> 4;

    const int bh = blockIdx.y;
    const int b  = bh >> 3;
    const int h  = bh & 7;
    const int q0 = blockIdx.x * 128;

    const ushort_t* Qb = Q  + (size_t)bh * SEQ * HDIM;
    const ushort_t* Kb = K  + (size_t)bh * SEQ * HDIM;
    const ushort_t* Vb = Vt + (size_t)bh * HDIM * SEQ;

    // Q fragments (registers, whole kernel). B-operand: n=q=l15, k=d=quad*8+j
    short8 qf0, qf1;
    {
        const ushort_t* qrow = Qb + (size_t)(q0 + w * 16 + l15) * HDIM + quad * 8;
        qf0 = *(const short8*)(qrow);
        qf1 = *(const short8*)(qrow + 32);
    }

    floatx4 of[4];
#pragma unroll
    for (int t = 0; t < 4; ++t) of[t] = (floatx4)0.0f;
    floatx4 ofl = (floatx4)0.0f;          // l accumulator via ones-MFMA

    short8 ones;
#pragma unroll
    for (int j = 0; j < 8; ++j) ones[j] = (short)0x3F80;   // bf16 1.0

    const floatx4 z4 = (floatx4)0.0f;

    // staging: wave w stages rows w*8..w*8+7 of each tile.
    // global source col16 is pre-swizzled so the LINEAR global_load_lds dest
    // (base + lane*16) lands the XOR-swizzled layout.
    const int srow = lane >> 3;                    // 0..7 = row&7
    const int scol = ((lane & 7) ^ srow) * 8;      // swizzled col (elems)
    const ushort_t* gk = Kb + (size_t)(w * 8 + srow) * HDIM + scol;
    const ushort_t* gv = Vb + (size_t)(w * 8 + srow) * SEQ + scol;
    ushort_t* lk0 = &Ks[0][w * 8 * 64];            // wave-uniform LDS bases
    ushort_t* lk1 = &Ks[1][w * 8 * 64];
    ushort_t* lv0 = &Vs[0][w * 8 * 64];
    ushort_t* lv1 = &Vs[1][w * 8 * 64];

    // fragment read offsets (swizzle-aware): global col16 c of row r sits at
    // LDS slot c ^ (r&7); r&7 == l15&7 for all t (t*16 = 0 mod 8).
    const int off0 = (quad ^ (l15 & 7)) * 8;       // elems, kv/d half 0
    const int off1 = off0 ^ 32;                    // (slot^4)*8, half 1

    auto tile = [&](const ushort_t* Kt, const ushort_t* Vt_) {
        // ---- S^T = K . Q^T ----
        floatx4 sacc[4];
        __builtin_amdgcn_s_setprio(1);
#pragma unroll
        for (int t = 0; t < 4; ++t) {
            const short8 kf0 = *(const short8*)&Kt[(t * 16 + l15) * 64 + off0];
            const short8 kf1 = *(const short8*)&Kt[(t * 16 + l15) * 64 + off1];
            floatx4 a = z4;
            a = __builtin_amdgcn_mfma_f32_16x16x32_bf16(kf0, qf0, a, 0, 0, 0);
            a = __builtin_amdgcn_mfma_f32_16x16x32_bf16(kf1, qf1, a, 0, 0, 0);
            sacc[t] = a;
        }
        __builtin_amdgcn_s_setprio(0);

        // ---- p = exp2(s) (raw v_exp_f32), pack pairs to bf16x2 ----
        // lane holds p for q=l15, kv = 16t + 4*quad + r
        unsigned w0[4], w1[4];
#pragma unroll
        for (int t = 0; t < 4; ++t) {
            const float p0 = __builtin_amdgcn_exp2f(sacc[t][0]);
            const float p1 = __builtin_amdgcn_exp2f(sacc[t][1]);
            const float p2 = __builtin_amdgcn_exp2f(sacc[t][2]);
            const float p3 = __builtin_amdgcn_exp2f(sacc[t][3]);
            asm("v_cvt_pk_bf16_f32 %0, %1, %2" : "=v"(w0[t]) : "v"(p0), "v"(p1));
            asm("v_cvt_pk_bf16_f32 %0, %1, %2" : "=v"(w1[t]) : "v"(p2), "v"(p3));
        }

        // ---- in-register P^T redistribution (dest b5'=t, b4'=src b5) ----
        unsigned a0 = w0[0], b0 = w0[1];
        asm("v_permlane32_swap_b32 %0, %1" : "+v"(a0), "+v"(b0));
        asm("v_permlane16_swap_b32 %0, %1" : "+v"(a0), "+v"(b0));
        unsigned a1 = w1[0], b1 = w1[1];
        asm("v_permlane32_swap_b32 %0, %1" : "+v"(a1), "+v"(b1));
        asm("v_permlane16_swap_b32 %0, %1" : "+v"(a1), "+v"(b1));
        unsigned a2 = w0[2], b2 = w0[3];
        asm("v_permlane32_swap_b32 %0, %1" : "+v"(a2), "+v"(b2));
        asm("v_permlane16_swap_b32 %0, %1" : "+v"(a2), "+v"(b2));
        unsigned a3 = w1[2], b3 = w1[3];
        asm("v_permlane32_swap_b32 %0, %1" : "+v"(a3), "+v"(b3));
        asm("v_permlane16_swap_b32 %0, %1" : "+v"(a3), "+v"(b3));

        union { unsigned u[4]; short8 s; } P0, P1;
        P0.u[0] = a0; P0.u[1] = a1; P0.u[2] = b0; P0.u[3] = b1;   // kv 0..31
        P1.u[0] = a2; P1.u[1] = a3; P1.u[2] = b2; P1.u[3] = b3;   // kv 32..63
        const short8 pf0 = P0.s;
        const short8 pf1 = P1.s;

        // ---- O^T += V^T . P^T ; l += 1 . P^T (MFMA pipe) ----
        __builtin_amdgcn_s_setprio(1);
        ofl = __builtin_amdgcn_mfma_f32_16x16x32_bf16(ones, pf0, ofl, 0, 0, 0);
        ofl = __builtin_amdgcn_mfma_f32_16x16x32_bf16(ones, pf1, ofl, 0, 0, 0);
#pragma unroll
        for (int t = 0; t < 4; ++t) {
            const short8 vf0 = *(const short8*)&Vt_[(t * 16 + l15) * 64 + off0];
            const short8 vf1 = *(const short8*)&Vt_[(t * 16 + l15) * 64 + off1];
            of[t] = __builtin_amdgcn_mfma_f32_16x16x32_bf16(vf0, pf0, of[t], 0, 0, 0);
            of[t] = __builtin_amdgcn_mfma_f32_16x16x32_bf16(vf1, pf1, of[t], 0, 0, 0);
        }
        __builtin_amdgcn_s_setprio(0);
    };

    // prologue: tile 0 into buf0
    async16(gk, lk0);
    async16(gv, lv0);

    for (int kt = 0; kt < SEQ; kt += 128) {
        __syncthreads();                       // drains buf0 loads (vmcnt(0))
        async16(gk + (size_t)(kt + 64) * HDIM, lk1);   // prefetch buf1
        async16(gv + (kt + 64), lv1);
        tile(Ks[0], Vs[0]);

        __syncthreads();                       // drains buf1 loads
        if (kt + 128 < SEQ) {
            async16(gk + (size_t)(kt + 128) * HDIM, lk0);  // prefetch buf0
            async16(gv + (kt + 128), lv0);
        }
        tile(Ks[1], Vs[1]);
    }

    // ---- epilogue: each lane already holds full l for its q=l15 ----
    const float inv = 1.f / ofl[0];

    const int s = q0 + w * 16 + l15;
    ushort_t* arow = Att + ((size_t)(b * SEQ + s)) * HID + h * HDIM;
#pragma unroll
    for (int t = 0; t < 4; ++t) {
        short4v pk;
#pragma unroll
        for (int r = 0; r < 4; ++r) pk[r] = (short)bf16_rne(of[t][r] * inv);
        *(short4v*)&arow[t * 16 + quad * 4] = pk;
    }
}

// ---------------------------------------------------------------------------
// Kernel 3: output projection, bf16 MFMA.  Round-15: 64x128 tile.
// Round-14 accounting: out = 6.4 GF in ~43-47 us (~140 TF) vs qkv's 430 TF
// with the SAME structure — the difference is occupancy: out's old grid
// (6,64) = 384 blocks = 1.5 blocks/CU (half the CUs run ONE block with full
// stage-latency exposure; qkv has 3/CU). Equal occupancy should give equal
// efficiency: 64x128 tile -> grid (6,128) = 768 blocks = 3 blocks/CU.
// acc[2][4]; LDS 24 KB; stage 2 async16 (A) + 4 (B); swizzle identical to
// round-9 (read rows still == l15 mod 8; staging swz = srow for all 8-row
// groups). B (Wot 0.77 MB) re-reads are L2-resident.
// ---------------------------------------------------------------------------
__global__ __launch_bounds__(256) void out_gemm_mfma(
    const ushort_t* __restrict__ Attb, const ushort_t* __restrict__ Wot,
    const float* __restrict__ bo, float* __restrict__ Y)
{
    __shared__ __align__(16) ushort_t As[64 * 64];
    __shared__ __align__(16) ushort_t Bs[128 * 64];

    const int m0 = blockIdx.y * 64;
    const int n0 = blockIdx.x * 128;

    const int tid  = threadIdx.x;
    const int lane = tid & 63;
    const int w    = tid >> 6;     // 0..3
    const int l15  = lane & 15;
    const int quad = lane >> 4;
    const int wrow = w >> 1;       // 32-row half
    const int wcol = w & 1;        // 64-col half

    const int srow = lane >> 3;                  // 0..7 = row&7
    const int scol = ((lane & 7) ^ srow) * 8;    // swizzled k elem offset

    // A: wave w stages rows w*16 + s*8 + srow (s<2); B: w*32 + s*8 + srow (s<4)
    const ushort_t* ga = Attb + (size_t)(m0 + w * 16 + srow) * HID + scol;
    const ushort_t* gb = Wot  + (size_t)(n0 + w * 32 + srow) * HID + scol;
    ushort_t* la = As + (w * 16) * 64;
    ushort_t* lb = Bs + (w * 32) * 64;

    floatx4 acc[2][4];
#pragma unroll
    for (int i = 0; i < 2; ++i)
#pragma unroll
        for (int j = 0; j < 4; ++j) acc[i][j] = (floatx4)0.0f;

    for (int kt = 0; kt < HID; kt += 64) {
#pragma unroll
        for (int s = 0; s < 2; ++s)
            async16(ga + (size_t)(s * 8) * HID + kt, la + s * 8 * 64);
#pragma unroll
        for (int s = 0; s < 4; ++s)
            async16(gb + (size_t)(s * 8) * HID + kt, lb + s * 8 * 64);
        __syncthreads();
#pragma unroll
        for (int half = 0; half < 2; ++half) {
            const int kk = ((half * 4 + quad) ^ (l15 & 7)) * 8;
            short8 af[2], bf[4];
#pragma unroll
            for (int t = 0; t < 2; ++t)
                af[t] = *(const short8*)&As[(wrow * 32 + t * 16 + l15) * 64 + kk];
#pragma unroll
            for (int t = 0; t < 4; ++t)
                bf[t] = *(const short8*)&Bs[(wcol * 64 + t * 16 + l15) * 64 + kk];
#pragma unroll
            for (int mi = 0; mi < 2; ++mi)
#pragma unroll
                for (int ni = 0; ni < 4; ++ni)
                    acc[mi][ni] = __builtin_amdgcn_mfma_f32_16x16x32_bf16(
                        bf[ni], af[mi], acc[mi][ni], 0, 0, 0);
        }
        __syncthreads();
    }

#pragma unroll
    for (int mi = 0; mi < 2; ++mi) {
        const int m = m0 + wrow * 32 + mi * 16 + l15;
#pragma unroll
        for (int ni = 0; ni < 4; ++ni) {
            const int nb = n0 + wcol * 64 + ni * 16 + quad * 4;
            const floatx4 b4 = *(const floatx4*)(bo + nb);
            floatx4 o;
#pragma unroll
            for (int r = 0; r < 4; ++r) o[r] = acc[mi][ni][r] + b4[r];
            *(floatx4*)&Y[(size_t)m * VDIM + nb] = o;
        }
    }
}

// ---------------------------------------------------------------------------
extern "C" void kernel_launch(void* const* d_in, const int* in_sizes, int n_in,
                              void* d_out, int out_size, void* d_ws, size_t ws_size,
                              hipStream_t stream)
{
    const float* text = (const float*)d_in[0];
    const float* Wq = (const float*)d_in[1];
    const float* bq = (const float*)d_in[2];
    const float* Wk = (const float*)d_in[3];
    const float* bk = (const float*)d_in[4];
    const float* Wv = (const float*)d_in[5];
    const float* bv = (const float*)d_in[6];
    const float* Wo = (const float*)d_in[7];
    const float* bo = (const float*)d_in[8];
    float* out = (float*)d_out;

    // ws layout (bf16): Xb | Wqkvt | Wot | Q | K | Vt | Attb  (~49 MB)
    ushort_t* Xb    = (ushort_t*)d_ws;
    ushort_t* Wqkvt = Xb + (size_t)MROWS * TDIM;
    ushort_t* Wot   = Wqkvt + (size_t)NQKV * TDIM;
    ushort_t* Qw    = Wot + (size_t)VDIM * HID;
    ushort_t* Kw    = Qw + (size_t)MROWS * HID;
    ushort_t* Vtw   = Kw + (size_t)MROWS * HID;
    ushort_t* Attb  = Vtw + (size_t)MROWS * HID;

    prepass<<<dim3(NCONV + 4 * 576), 256, 0, stream>>>(
        text, Wq, Wk, Wv, Wo, Xb, Wqkvt, Wot);
    qkv_gemm_mfma<<<dim3(12, 64), 256, 0, stream>>>(Xb, Wqkvt, bq, bk, bv, Qw, Kw, Vtw);
    flash_attn_mfma<<<dim3(16, 32), 512, 0, stream>>>(Qw, Kw, Vtw, Attb);
    out_gemm_mfma<<<dim3(6, 128), 256, 0, stream>>>(Attb, Wot, bo, out);
}